// Round 13
// baseline (791.248 us; speedup 1.0000x reference)
//
#include <hip/hip_runtime.h>
#include <hip/hip_bf16.h>

typedef __bf16 bf16;
typedef __bf16 bf16x4 __attribute__((ext_vector_type(4)));
typedef __bf16 bf16x8 __attribute__((ext_vector_type(8)));
typedef float f32x4 __attribute__((ext_vector_type(4)));

#define NB   32768
#define EMB  768
#define MSUB 32
#define KC   256
#define DSUB 24

// DIAGNOSTIC ROUND: pq_scores9 body replayed 3x (idempotent writes) so it
// exceeds the harness's ~650us fillBuffer dispatches and surfaces in the
// rocprof top-5 with real counters. Per-pass time = dur/3.

// ws layout (bytes):
//   [0,     512K )  cb_pad: bf16 [32][256][32]  (d padded 24->32 with zeros)
//   [1M,  2.125M)  rot_bf: bf16 [768][768]
//   [4M,    54M )  xr2   : bf16 [tile(2048)][m(32)][r(16)][d(24)]

__device__ __forceinline__ bf16x8 cvt8(float4 a, float4 b) {
    bf16x8 r;
    r[0] = (bf16)a.x; r[1] = (bf16)a.y; r[2] = (bf16)a.z; r[3] = (bf16)a.w;
    r[4] = (bf16)b.x; r[5] = (bf16)b.y; r[6] = (bf16)b.z; r[7] = (bf16)b.w;
    return r;
}

// LDS-only barrier: waits LDS ops (lgkmcnt) but NOT global stores (vmcnt).
__device__ __forceinline__ void lds_barrier() {
    asm volatile("s_waitcnt lgkmcnt(0)" ::: "memory");
    __builtin_amdgcn_s_barrier();
    __builtin_amdgcn_sched_barrier(0);
}

// ---------------------------------------------------------------- kernel 0
__global__ __launch_bounds__(256, 4)
void pq_prep(const float* __restrict__ cb, const float* __restrict__ rot,
             bf16* __restrict__ cb_pad, bf16* __restrict__ rot_bf) {
    const int b = blockIdx.x;
    const int t = threadIdx.x;
    if (b < 288) {                       // rot: 768*768 = 288*2048
        const int o = b * 2048 + t * 8;
        float4 a0 = *(const float4*)(rot + o);
        float4 a1 = *(const float4*)(rot + o + 4);
        *(bf16x8*)(rot_bf + o) = cvt8(a0, a1);
    } else {                             // cb pad+cvt: [m][k][24] -> bf16 [m][k][32]
        const int o  = (b - 288) * 2048 + t * 8;   // 32*256*32 = 128*2048
        const int m  = o >> 13;
        const int k  = (o >> 5) & 255;
        const int d0 = o & 31;           // 0,8,16,24
        bf16x8 v;
        if (d0 < DSUB) {
            const float* cp = cb + (size_t)(m * KC + k) * DSUB + d0;
            v = cvt8(*(const float4*)cp, *(const float4*)(cp + 4));
        } else {
            const float4 fz = {0.f, 0.f, 0.f, 0.f};
            v = cvt8(fz, fz);
        }
        *(bf16x8*)(cb_pad + o) = v;
    }
}

// ---------------------------------------------------------------- kernel 1
__global__ __launch_bounds__(512, 3)
void pq_rot(const float* __restrict__ x, const bf16* __restrict__ rot_bf,
            bf16* __restrict__ xr2) {
    __shared__ bf16 g_lds[96 * 32 * 8];   // x bf16 granules [e8][row][slot], 48 KiB

    const int tid  = threadIdx.x;
    const int w    = tid >> 6;
    const int lane = tid & 63;
    const int l15  = lane & 15;
    const int lg   = lane >> 4;
    const int rowbase = blockIdx.x * 32;

    #pragma unroll
    for (int i = 0; i < 6; ++i) {
        const int oct = i * 512 + tid;
        const int row = oct & 31;
        const int e8  = oct >> 5;
        const float* xp = x + (size_t)(rowbase + row) * EMB + e8 * 8;
        *(bf16x8*)&g_lds[(e8 * 32 + row) * 8] =
            cvt8(*(const float4*)xp, *(const float4*)(xp + 4));
    }
    __syncthreads();

    f32x4 acc[2][6];
    #pragma unroll
    for (int rt = 0; rt < 2; ++rt)
        #pragma unroll
        for (int jt = 0; jt < 6; ++jt)
            acc[rt][jt] = (f32x4){0.f, 0.f, 0.f, 0.f};

    const int jbase = w * 96;
    #pragma unroll 2
    for (int e0 = 0; e0 < EMB; e0 += 32) {
        bf16x8 xfrag[2];
        #pragma unroll
        for (int rt = 0; rt < 2; ++rt)
            xfrag[rt] = *(const bf16x8*)&g_lds[(((e0 >> 3) + lg) * 32 + rt * 16 + l15) * 8];
        #pragma unroll
        for (int jt = 0; jt < 6; ++jt) {
            const bf16* bp = rot_bf + (size_t)(jbase + jt * 16 + l15) * EMB + e0 + lg * 8;
            bf16x8 rotfrag = *(const bf16x8*)bp;
            acc[0][jt] = __builtin_amdgcn_mfma_f32_16x16x32_bf16(rotfrag, xfrag[0], acc[0][jt], 0, 0, 0);
            acc[1][jt] = __builtin_amdgcn_mfma_f32_16x16x32_bf16(rotfrag, xfrag[1], acc[1][jt], 0, 0, 0);
        }
    }

    // epilogue into scores-native xr2 layout
    #pragma unroll
    for (int rt = 0; rt < 2; ++rt) {
        #pragma unroll
        for (int jt = 0; jt < 6; ++jt) {
            const int j0 = jbase + jt * 16 + lg * 4;
            const int m  = j0 / DSUB;
            const int d0 = j0 % DSUB;
            bf16x4 v;
            #pragma unroll
            for (int r = 0; r < 4; ++r) v[r] = (bf16)acc[rt][jt][r];
            bf16* p = xr2 + ((size_t)((blockIdx.x * 2 + rt) * MSUB + m) * 16 + l15) * DSUB + d0;
            *(bf16x4*)p = v;
        }
    }
}

// ---------------------------------------------------------------- kernel 2
// R12 body, replayed REPLAY times (idempotent) for counter visibility.
#define STG_ROW 1044
#define REPLAY 3
__global__ __launch_bounds__(256, 2)
void pq_scores9(const bf16* __restrict__ xr2, const bf16* __restrict__ cb_pad,
                float* __restrict__ out) {
    __shared__ float stg[16 * STG_ROW];   // 66,816 B -> 2 blocks/CU

    const int tid  = threadIdx.x;
    const int lane = tid & 63;
    const int w    = tid >> 6;          // 0..3
    const int l15  = lane & 15;
    const int hi   = lane >> 4;         // 0..3

    const int bid = (int)blockIdx.x;
    const int swz = (bid & 7) * 256 + (bid >> 3);
    const int rowbase = swz * 16;

    #pragma unroll 1
    for (int rep = 0; rep < REPLAY; ++rep) {
        #pragma unroll 1
        for (int mm = 0; mm < 8; ++mm) {
            const int m = mm * 4 + w;

            const bf16* xp = xr2 + ((size_t)(swz * MSUB + m) * 16 + l15) * DSUB + hi * 8;
            bf16x8 xfrag = *(const bf16x8*)xp;

            const bf16* cbm = cb_pad + (size_t)m * (KC * 32);
            f32x4 acc[16];
            #pragma unroll
            for (int kt = 0; kt < 16; ++kt) {
                bf16x8 cfrag = *(const bf16x8*)(cbm + (kt * 16 + l15) * 32 + hi * 8);
                acc[kt] = __builtin_amdgcn_mfma_f32_16x16x32_bf16(
                    cfrag, xfrag, (f32x4){0.f, 0.f, 0.f, 0.f}, 0, 0, 0);
            }

            #pragma unroll
            for (int kt = 0; kt < 16; ++kt)
                *(f32x4*)&stg[l15 * STG_ROW + w * 260 + kt * 16 + hi * 4] = acc[kt];

            lds_barrier();

            #pragma unroll
            for (int j = 0; j < 4; ++j) {
                const int row = w * 4 + j;
                float* op = out + ((size_t)(rowbase + row) * MSUB + mm * 4) * KC + 4 * lane;
                #pragma unroll
                for (int ms = 0; ms < 4; ++ms) {
                    f32x4 v = *(const f32x4*)&stg[row * STG_ROW + ms * 260 + 4 * lane];
                    *(f32x4*)(op + ms * KC) = v;
                }
            }

            lds_barrier();
        }
    }
}

extern "C" void kernel_launch(void* const* d_in, const int* in_sizes, int n_in,
                              void* d_out, int out_size, void* d_ws, size_t ws_size,
                              hipStream_t stream) {
    const float* x   = (const float*)d_in[0];   // [32768, 768]
    const float* cbk = (const float*)d_in[1];   // [32, 256, 24]
    const float* rot = (const float*)d_in[2];   // [768, 768]
    float* out = (float*)d_out;                 // [32768, 32, 256]

    char* ws = (char*)d_ws;
    bf16* cb_pad = (bf16*)(ws);
    bf16* rot_bf = (bf16*)(ws + (1u << 20));
    bf16* xr2    = (bf16*)(ws + (4u << 20));

    hipLaunchKernelGGL(pq_prep,     dim3(416),  dim3(256), 0, stream, cbk, rot, cb_pad, rot_bf);
    hipLaunchKernelGGL(pq_rot,      dim3(1024), dim3(512), 0, stream, x, rot_bf, xr2);
    hipLaunchKernelGGL(pq_scores9,  dim3(2048), dim3(256), 0, stream, xr2, cb_pad, out);
}

// Round 14
// 345.946 us; speedup vs baseline: 2.2872x; 2.2872x over previous
//
#include <hip/hip_runtime.h>
#include <hip/hip_bf16.h>

typedef __bf16 bf16;
typedef __bf16 bf16x4 __attribute__((ext_vector_type(4)));
typedef __bf16 bf16x8 __attribute__((ext_vector_type(8)));
typedef float f32x4 __attribute__((ext_vector_type(4)));

#define NB   32768
#define EMB  768
#define MSUB 32
#define KC   256
#define DSUB 24

// ws layout (bytes):
//   [0,     512K )  cb_pad: bf16 [32][256][32]  (d padded 24->32 with zeros)
//   [1M,  2.125M)  rot_f : bf16 fragment-contiguous rotation:
//                  rot_f[((jt*24)+et)*512 + lane*8 + i] = rot[jt*16+(lane&15)]
//                                                            [et*32+(lane>>4)*8+i]
//                  -> one MFMA A-operand = one contiguous 1KB wave-load
//   [4M,    54M )  xr2   : bf16 [tile(2048)][m(32)][r(16)][d(24)]

__device__ __forceinline__ bf16x8 cvt8(float4 a, float4 b) {
    bf16x8 r;
    r[0] = (bf16)a.x; r[1] = (bf16)a.y; r[2] = (bf16)a.z; r[3] = (bf16)a.w;
    r[4] = (bf16)b.x; r[5] = (bf16)b.y; r[6] = (bf16)b.z; r[7] = (bf16)b.w;
    return r;
}

// LDS-only barrier: waits LDS ops (lgkmcnt) but NOT global stores (vmcnt).
__device__ __forceinline__ void lds_barrier() {
    asm volatile("s_waitcnt lgkmcnt(0)" ::: "memory");
    __builtin_amdgcn_s_barrier();
    __builtin_amdgcn_sched_barrier(0);
}

// ---------------------------------------------------------------- kernel 0
__global__ __launch_bounds__(256, 4)
void pq_prep(const float* __restrict__ cb, const float* __restrict__ rot,
             bf16* __restrict__ cb_pad, bf16* __restrict__ rot_f) {
    const int b = blockIdx.x;
    const int t = threadIdx.x;
    if (b < 288) {                       // rot -> fragment-contiguous rot_f
        const int o     = b * 2048 + t * 8;    // flat rot_f index
        const int chunk = o >> 9;              // (jt*24 + et), 1152 chunks
        const int lane8 = o & 511;
        const int l15   = (lane8 >> 3) & 15;
        const int lg    = lane8 >> 7;
        const int jj    = (chunk / 24) * 16 + l15;
        const int ee    = (chunk % 24) * 32 + lg * 8;
        const float* rp = rot + (size_t)jj * EMB + ee;
        *(bf16x8*)(rot_f + o) = cvt8(*(const float4*)rp, *(const float4*)(rp + 4));
    } else {                             // cb pad+cvt: [m][k][24] -> bf16 [m][k][32]
        const int o  = (b - 288) * 2048 + t * 8;   // 32*256*32 = 128*2048
        const int m  = o >> 13;
        const int k  = (o >> 5) & 255;
        const int d0 = o & 31;           // 0,8,16,24
        bf16x8 v;
        if (d0 < DSUB) {
            const float* cp = cb + (size_t)(m * KC + k) * DSUB + d0;
            v = cvt8(*(const float4*)cp, *(const float4*)(cp + 4));
        } else {
            const float4 fz = {0.f, 0.f, 0.f, 0.f};
            v = cvt8(fz, fz);
        }
        *(bf16x8*)(cb_pad + o) = v;
    }
}

// ---------------------------------------------------------------- kernel 1
// xr = x @ rot^T via swapped MFMA: D[j][row] = mfma(A=rot_frag, B=x_frag).
// rot fragments now load CONTIGUOUSLY from rot_f (1KB/wave-instr, L2-hot)
// instead of 16-segment gathers at 1536B stride.
__global__ __launch_bounds__(512, 3)
void pq_rot(const float* __restrict__ x, const bf16* __restrict__ rot_f,
            bf16* __restrict__ xr2) {
    __shared__ bf16 g_lds[96 * 32 * 8];   // x bf16 granules [e8][row][slot], 48 KiB

    const int tid  = threadIdx.x;
    const int w    = tid >> 6;
    const int lane = tid & 63;
    const int l15  = lane & 15;
    const int lg   = lane >> 4;
    const int rowbase = blockIdx.x * 32;

    #pragma unroll
    for (int i = 0; i < 6; ++i) {
        const int oct = i * 512 + tid;
        const int row = oct & 31;
        const int e8  = oct >> 5;
        const float* xp = x + (size_t)(rowbase + row) * EMB + e8 * 8;
        *(bf16x8*)&g_lds[(e8 * 32 + row) * 8] =
            cvt8(*(const float4*)xp, *(const float4*)(xp + 4));
    }
    __syncthreads();

    f32x4 acc[2][6];
    #pragma unroll
    for (int rt = 0; rt < 2; ++rt)
        #pragma unroll
        for (int jt = 0; jt < 6; ++jt)
            acc[rt][jt] = (f32x4){0.f, 0.f, 0.f, 0.f};

    const int jt0 = w * 6;               // wave owns j-tiles jt0..jt0+5
    #pragma unroll 2
    for (int et = 0; et < 24; ++et) {
        bf16x8 xfrag[2];
        #pragma unroll
        for (int rt = 0; rt < 2; ++rt)
            xfrag[rt] = *(const bf16x8*)&g_lds[(((et << 2) + lg) * 32 + rt * 16 + l15) * 8];
        #pragma unroll
        for (int jt = 0; jt < 6; ++jt) {
            const bf16* rp = rot_f + (((size_t)(jt0 + jt) * 24 + et) << 9) + lane * 8;
            bf16x8 rotfrag = *(const bf16x8*)rp;
            acc[0][jt] = __builtin_amdgcn_mfma_f32_16x16x32_bf16(rotfrag, xfrag[0], acc[0][jt], 0, 0, 0);
            acc[1][jt] = __builtin_amdgcn_mfma_f32_16x16x32_bf16(rotfrag, xfrag[1], acc[1][jt], 0, 0, 0);
        }
    }

    // epilogue into scores-native xr2 layout
    const int jbase = w * 96;
    #pragma unroll
    for (int rt = 0; rt < 2; ++rt) {
        #pragma unroll
        for (int jt = 0; jt < 6; ++jt) {
            const int j0 = jbase + jt * 16 + lg * 4;
            const int m  = j0 / DSUB;
            const int d0 = j0 % DSUB;
            bf16x4 v;
            #pragma unroll
            for (int r = 0; r < 4; ++r) v[r] = (bf16)acc[rt][jt][r];
            bf16* p = xr2 + ((size_t)((blockIdx.x * 2 + rt) * MSUB + m) * 16 + l15) * DSUB + d0;
            *(bf16x4*)p = v;
        }
    }
}

// ---------------------------------------------------------------- kernel 2
// scores via MFMA (R12 body; steady-state measured at ~180us/pass = 6 TB/s).
#define STG_ROW 1044
__global__ __launch_bounds__(256, 2)
void pq_scores9(const bf16* __restrict__ xr2, const bf16* __restrict__ cb_pad,
                float* __restrict__ out) {
    __shared__ float stg[16 * STG_ROW];   // 66,816 B -> 2 blocks/CU

    const int tid  = threadIdx.x;
    const int lane = tid & 63;
    const int w    = tid >> 6;          // 0..3
    const int l15  = lane & 15;
    const int hi   = lane >> 4;         // 0..3

    const int bid = (int)blockIdx.x;
    const int swz = (bid & 7) * 256 + (bid >> 3);
    const int rowbase = swz * 16;

    #pragma unroll 1
    for (int mm = 0; mm < 8; ++mm) {
        const int m = mm * 4 + w;

        const bf16* xp = xr2 + ((size_t)(swz * MSUB + m) * 16 + l15) * DSUB + hi * 8;
        bf16x8 xfrag = *(const bf16x8*)xp;

        const bf16* cbm = cb_pad + (size_t)m * (KC * 32);
        f32x4 acc[16];
        #pragma unroll
        for (int kt = 0; kt < 16; ++kt) {
            bf16x8 cfrag = *(const bf16x8*)(cbm + (kt * 16 + l15) * 32 + hi * 8);
            acc[kt] = __builtin_amdgcn_mfma_f32_16x16x32_bf16(
                cfrag, xfrag, (f32x4){0.f, 0.f, 0.f, 0.f}, 0, 0, 0);
        }

        #pragma unroll
        for (int kt = 0; kt < 16; ++kt)
            *(f32x4*)&stg[l15 * STG_ROW + w * 260 + kt * 16 + hi * 4] = acc[kt];

        lds_barrier();

        #pragma unroll
        for (int j = 0; j < 4; ++j) {
            const int row = w * 4 + j;
            float* op = out + ((size_t)(rowbase + row) * MSUB + mm * 4) * KC + 4 * lane;
            #pragma unroll
            for (int ms = 0; ms < 4; ++ms) {
                f32x4 v = *(const f32x4*)&stg[row * STG_ROW + ms * 260 + 4 * lane];
                *(f32x4*)(op + ms * KC) = v;
            }
        }

        lds_barrier();
    }
}

extern "C" void kernel_launch(void* const* d_in, const int* in_sizes, int n_in,
                              void* d_out, int out_size, void* d_ws, size_t ws_size,
                              hipStream_t stream) {
    const float* x   = (const float*)d_in[0];   // [32768, 768]
    const float* cbk = (const float*)d_in[1];   // [32, 256, 24]
    const float* rot = (const float*)d_in[2];   // [768, 768]
    float* out = (float*)d_out;                 // [32768, 32, 256]

    char* ws = (char*)d_ws;
    bf16* cb_pad = (bf16*)(ws);
    bf16* rot_f  = (bf16*)(ws + (1u << 20));
    bf16* xr2    = (bf16*)(ws + (4u << 20));

    hipLaunchKernelGGL(pq_prep,     dim3(416),  dim3(256), 0, stream, cbk, rot, cb_pad, rot_f);
    hipLaunchKernelGGL(pq_rot,      dim3(1024), dim3(512), 0, stream, x, rot_f, xr2);
    hipLaunchKernelGGL(pq_scores9,  dim3(2048), dim3(256), 0, stream, xr2, cb_pad, out);
}

// Round 16
// 299.198 us; speedup vs baseline: 2.6446x; 1.1562x over previous
//
#include <hip/hip_runtime.h>
#include <hip/hip_bf16.h>

typedef __bf16 bf16;
typedef __bf16 bf16x4 __attribute__((ext_vector_type(4)));
typedef __bf16 bf16x8 __attribute__((ext_vector_type(8)));
typedef float f32x4 __attribute__((ext_vector_type(4)));

#define NB   32768
#define EMB  768
#define MSUB 32
#define KC   256
#define DSUB 24

// ws layout (bytes):
//   [0,     512K )  cb_pad: bf16 [32][256][32]  (d padded 24->32 with zeros)
//   [1M,  2.125M)  rot_f : bf16 fragment-contiguous rotation (see R14)

__device__ __forceinline__ bf16x8 cvt8(float4 a, float4 b) {
    bf16x8 r;
    r[0] = (bf16)a.x; r[1] = (bf16)a.y; r[2] = (bf16)a.z; r[3] = (bf16)a.w;
    r[4] = (bf16)b.x; r[5] = (bf16)b.y; r[6] = (bf16)b.z; r[7] = (bf16)b.w;
    return r;
}

// LDS-only barrier: waits LDS ops (lgkmcnt) but NOT global stores (vmcnt).
__device__ __forceinline__ void lds_barrier() {
    asm volatile("s_waitcnt lgkmcnt(0)" ::: "memory");
    __builtin_amdgcn_s_barrier();
    __builtin_amdgcn_sched_barrier(0);
}

// ---------------------------------------------------------------- kernel 0
__global__ __launch_bounds__(256, 4)
void pq_prep(const float* __restrict__ cb, const float* __restrict__ rot,
             bf16* __restrict__ cb_pad, bf16* __restrict__ rot_f) {
    const int b = blockIdx.x;
    const int t = threadIdx.x;
    if (b < 288) {                       // rot -> fragment-contiguous rot_f
        const int o     = b * 2048 + t * 8;
        const int chunk = o >> 9;              // (jt*24 + et)
        const int lane8 = o & 511;
        const int l15   = (lane8 >> 3) & 15;
        const int lg    = lane8 >> 7;
        const int jj    = (chunk / 24) * 16 + l15;
        const int ee    = (chunk % 24) * 32 + lg * 8;
        const float* rp = rot + (size_t)jj * EMB + ee;
        *(bf16x8*)(rot_f + o) = cvt8(*(const float4*)rp, *(const float4*)(rp + 4));
    } else {                             // cb pad+cvt: [m][k][24] -> bf16 [m][k][32]
        const int o  = (b - 288) * 2048 + t * 8;
        const int m  = o >> 13;
        const int k  = (o >> 5) & 255;
        const int d0 = o & 31;
        bf16x8 v;
        if (d0 < DSUB) {
            const float* cp = cb + (size_t)(m * KC + k) * DSUB + d0;
            v = cvt8(*(const float4*)cp, *(const float4*)(cp + 4));
        } else {
            const float4 fz = {0.f, 0.f, 0.f, 0.f};
            v = cvt8(fz, fz);
        }
        *(bf16x8*)(cb_pad + o) = v;
    }
}

// ---------------------------------------------------------------- kernel 1
// FUSED rot + scores. 512 thr / 32 rows / block, grid 1024, LDS 80 KB ->
// 2 blocks/CU: one block's store-drain overlaps the other's rot MFMA.
// Phase A: xr = x @ rot^T (R14 body); epilogue writes xr to LDS
//   xl[(m*32+row)*24 + d] bf16 (scores-native).
// Phase B: 32 m-phases; wave w: row-half rt=w>>2, k-tiles kb=(w&3)*4..+3;
//   4 MFMA -> XOR-swizzled stg slab -> lgkm-barrier -> drain full 1KB lines.
// R15 bug fixed: drain reads LDS pos (4*lane)^ssw (true k = 4*lane) and
// stores to out k = 4*lane (NOT kidx) -- un-swizzle on the store address.
__global__ __launch_bounds__(512, 4)
void pq_fused(const float* __restrict__ x, const bf16* __restrict__ rot_f,
              const bf16* __restrict__ cb_pad, float* __restrict__ out) {
    __shared__ __align__(16) char smem[81920];
    bf16*  xl  = (bf16*)smem;                  // 49152 B: x granules, then xr
    float* stg = (float*)(smem + 49152);       // 32768 B: one m-slice slab

    const int tid  = threadIdx.x;
    const int w    = tid >> 6;          // 0..7
    const int lane = tid & 63;
    const int l15  = lane & 15;
    const int lg   = lane >> 4;         // 0..3 (also 'hi' in phase B)

    // XCD-bijective swizzle: 1024 blocks, 128 contiguous per XCD
    const int bid = (int)blockIdx.x;
    const int swz = (bid & 7) * 128 + (bid >> 3);
    const int rowbase = swz * 32;

    // ---- Phase A: stage x -> bf16 granules [e8][row][slot] ----
    #pragma unroll
    for (int i = 0; i < 6; ++i) {
        const int oct = i * 512 + tid;
        const int row = oct & 31;
        const int e8  = oct >> 5;
        const float* xp = x + (size_t)(rowbase + row) * EMB + e8 * 8;
        *(bf16x8*)&xl[(e8 * 32 + row) * 8] =
            cvt8(*(const float4*)xp, *(const float4*)(xp + 4));
    }
    __syncthreads();

    f32x4 acc[2][6];
    #pragma unroll
    for (int rt = 0; rt < 2; ++rt)
        #pragma unroll
        for (int jt = 0; jt < 6; ++jt)
            acc[rt][jt] = (f32x4){0.f, 0.f, 0.f, 0.f};

    const int jt0 = w * 6;
    #pragma unroll 2
    for (int et = 0; et < 24; ++et) {
        bf16x8 xfrag[2];
        #pragma unroll
        for (int rt = 0; rt < 2; ++rt)
            xfrag[rt] = *(const bf16x8*)&xl[(((et << 2) + lg) * 32 + rt * 16 + l15) * 8];
        #pragma unroll
        for (int jt = 0; jt < 6; ++jt) {
            const bf16* rp = rot_f + (((size_t)(jt0 + jt) * 24 + et) << 9) + lane * 8;
            bf16x8 rotfrag = *(const bf16x8*)rp;
            acc[0][jt] = __builtin_amdgcn_mfma_f32_16x16x32_bf16(rotfrag, xfrag[0], acc[0][jt], 0, 0, 0);
            acc[1][jt] = __builtin_amdgcn_mfma_f32_16x16x32_bf16(rotfrag, xfrag[1], acc[1][jt], 0, 0, 0);
        }
    }

    lds_barrier();   // all waves done READING x granules

    // epilogue: overwrite xl with xr, layout [(m*32+row)*24 + d]
    const int jbase = w * 96;
    #pragma unroll
    for (int rt = 0; rt < 2; ++rt) {
        #pragma unroll
        for (int jt = 0; jt < 6; ++jt) {
            const int j0 = jbase + jt * 16 + lg * 4;
            const int m  = j0 / DSUB;
            const int d0 = j0 % DSUB;
            const int row = rt * 16 + l15;
            bf16x4 v;
            #pragma unroll
            for (int r = 0; r < 4; ++r) v[r] = (bf16)acc[rt][jt][r];
            *(bf16x4*)&xl[(m * 32 + row) * 24 + d0] = v;
        }
    }

    lds_barrier();   // xr visible to all waves

    // ---- Phase B: scores. wave w: rt = w>>2 (row half), kb = (w&3)*4 ----
    const int rt = w >> 2;
    const int kb = (w & 3) * 4;
    const int hi = lg;
    const int srow = rt * 16 + l15;            // row this lane computes
    const int ssw  = (srow & 7) << 2;          // stage XOR swizzle

    #pragma unroll 1
    for (int m = 0; m < MSUB; ++m) {
        // xs B-frag from LDS; clamp keeps the (m=31,row=31,hi=3) overrun
        // inside xl (finite bf16 x cb_pad zeros = 0)
        int off = (m * 32 + srow) * 24 + hi * 8;
        off = off > 24568 ? 24568 : off;
        bf16x8 xfrag = *(const bf16x8*)&xl[off];

        const bf16* cbm = cb_pad + (size_t)m * (KC * 32);
        f32x4 a4[4];
        #pragma unroll
        for (int kk = 0; kk < 4; ++kk) {
            const int kt = kb + kk;
            bf16x8 cfrag = *(const bf16x8*)(cbm + (kt * 16 + l15) * 32 + hi * 8);
            a4[kk] = __builtin_amdgcn_mfma_f32_16x16x32_bf16(
                cfrag, xfrag, (f32x4){0.f, 0.f, 0.f, 0.f}, 0, 0, 0);
        }

        // stage: D[kc = kt*16+hi*4+r][row = srow], XOR-swizzled k-chunk
        #pragma unroll
        for (int kk = 0; kk < 4; ++kk) {
            const int kidx = (((kb + kk) * 16 + hi * 4) ^ ssw);
            *(f32x4*)&stg[srow * 256 + kidx] = a4[kk];
        }

        lds_barrier();   // slab complete (lgkm only; stores keep flowing)

        // drain: wave w -> rows w*4..+3, full 1KB line each.
        // LDS pos (4*lane)^ssw holds true k = 4*lane -> store at 4*lane.
        #pragma unroll
        for (int j = 0; j < 4; ++j) {
            const int drow = w * 4 + j;
            const int kidx = (4 * lane) ^ ((drow & 7) << 2);
            f32x4 v = *(const f32x4*)&stg[drow * 256 + kidx];
            *(f32x4*)(out + ((size_t)(rowbase + drow) * MSUB + m) * KC + 4 * lane) = v;
        }

        lds_barrier();   // drain reads done before next stage overwrites
    }
}

extern "C" void kernel_launch(void* const* d_in, const int* in_sizes, int n_in,
                              void* d_out, int out_size, void* d_ws, size_t ws_size,
                              hipStream_t stream) {
    const float* x   = (const float*)d_in[0];   // [32768, 768]
    const float* cbk = (const float*)d_in[1];   // [32, 256, 24]
    const float* rot = (const float*)d_in[2];   // [768, 768]
    float* out = (float*)d_out;                 // [32768, 32, 256]

    char* ws = (char*)d_ws;
    bf16* cb_pad = (bf16*)(ws);
    bf16* rot_f  = (bf16*)(ws + (1u << 20));

    hipLaunchKernelGGL(pq_prep,  dim3(416),  dim3(256), 0, stream, cbk, rot, cb_pad, rot_f);
    hipLaunchKernelGGL(pq_fused, dim3(1024), dim3(512), 0, stream, x, rot_f, cb_pad, out);
}